// Round 8
// baseline (646.136 us; speedup 1.0000x reference)
//
#include <hip/hip_runtime.h>
#include <hip/hip_bf16.h>

static inline int cdiv(int a, int b){ return (a+b-1)/b; }

#define LEAKY(x) ((x) >= 0.f ? (x) : 0.2f*(x))

#define NBK   256          // nodes per dst-bucket
#define NBKSH 8
#define CAP   5120         // tmp slots per bucket (mean 4096, ~16 sigma margin)

__device__ inline unsigned short bf16bits(float f){
  __hip_bfloat16 h = __float2bfloat16(f);
  return *reinterpret_cast<unsigned short*>(&h);
}

// ---------------- CSR build, phase A: bin edges by dst bucket ----------------
// 128 blocks -> per-bucket runs of ~32 edges (~128B full lines).

__global__ __launch_bounds__(256) void binA(const int* __restrict__ src,
    const int* __restrict__ dst, int* __restrict__ acur, unsigned int* __restrict__ tmp,
    int E, int B, int epb)
{
  __shared__ int cnt1[512], cnt2[512], gbase[512];
  const int tid = threadIdx.x;
  for (int j = tid; j < 512; j += 256) { cnt1[j] = 0; cnt2[j] = 0; }
  __syncthreads();
  const int beg = blockIdx.x*epb, end = min(E, beg+epb);
  for (int e = beg+tid; e < end; e += 256) atomicAdd(&cnt1[dst[e]>>NBKSH], 1);
  __syncthreads();
  for (int j = tid; j < B; j += 256) gbase[j] = atomicAdd(&acur[j], cnt1[j]);
  __syncthreads();
  for (int e = beg+tid; e < end; e += 256) {
    int s = src[e], d = dst[e];
    int b = d >> NBKSH;
    int tk = atomicAdd(&cnt2[b], 1);
    int slot = gbase[b] + tk;
    if (slot < CAP)                     // safety; never hit for this graph
      tmp[(size_t)b*CAP + slot] = ((unsigned)s << NBKSH) | (unsigned)(d & (NBK-1));
  }
}

// ---------------- phase B: scan bucket counts -> bucket bases; off[N]=E ----------------

__global__ __launch_bounds__(512) void bucket_scan(const int* __restrict__ acur,
    int* __restrict__ bbase, int* __restrict__ off, int B, int N, int E)
{
  __shared__ int wsum[8];
  const int tid = threadIdx.x, lane = tid & 63, wave = tid >> 6;
  int v = (tid < B) ? acur[tid] : 0;
  int x = v;
  #pragma unroll
  for (int s = 1; s < 64; s <<= 1) { int t = __shfl_up(x, s); if (lane >= s) x += t; }
  if (lane == 63) wsum[wave] = x;
  __syncthreads();
  if (tid == 0) { int r = 0; for (int w = 0; w < 8; w++) { int t = wsum[w]; wsum[w] = r; r += t; } }
  __syncthreads();
  int excl = wsum[wave] + x - v;
  if (tid < B)    bbase[tid] = excl;
  if (tid == B-1) bbase[B]   = excl + v;
  if (tid == 0)   off[N]     = E;
}

// ---------------- phase C: per-bucket local CSR (one block per bucket) ----------------

__global__ __launch_bounds__(256) void binC(const unsigned int* __restrict__ tmp,
    const int* __restrict__ acur, const int* __restrict__ bbase,
    int* __restrict__ off, int2* __restrict__ csr, int N)
{
  __shared__ int sA[NBK], sB[NBK];
  const int b = blockIdx.x, tid = threadIdx.x;
  const int m = min(acur[b], CAP);
  const int base = bbase[b];
  const int n0 = b*NBK;
  const int nn = min(NBK, N - n0);
  if (tid < NBK) sA[tid] = 0;
  __syncthreads();
  const unsigned int* tb = tmp + (size_t)b*CAP;
  for (int i = tid; i < m; i += 256) atomicAdd(&sA[tb[i] & (NBK-1)], 1);
  __syncthreads();
  int* in = sA; int* ob = sB;
  for (int st = 1; st < NBK; st <<= 1) {
    if (tid < NBK) { int v = in[tid]; if (tid >= st) v += in[tid-st]; ob[tid] = v; }
    __syncthreads();
    int* t = in; in = ob; ob = t;
  }
  if (tid < NBK) ob[tid] = tid ? in[tid-1] : 0;   // exclusive into ob
  __syncthreads();
  if (tid < nn) off[n0 + tid] = base + ob[tid];
  __syncthreads();
  for (int i = tid; i < m; i += 256) {       // ob doubles as per-node cursor
    unsigned v = tb[i];
    int local = v & (NBK-1);
    int pos = atomicAdd(&ob[local], 1);
    csr[base + pos] = int2{(int)(v >> NBKSH), n0 + local};
  }
}

// -------- fused node linear K=128: feat=X@W1 (bf16 head-major) AND res=X@rW1 --------
// 32-node tile; thread t: cols c0=(t&15)*4..+3, nodes n0=(t>>4)*2..+1. One X staging.

__global__ __launch_bounds__(256) void lin128_fused(const float* __restrict__ X,
    const float* __restrict__ W, const float* __restrict__ RW,
    const float* __restrict__ al, const float* __restrict__ ar,
    unsigned short* __restrict__ featH, float* __restrict__ el, float* __restrict__ er,
    float* __restrict__ res, int n, int N)
{
  __shared__ float Ws[128*64];
  __shared__ float Rs[128*64];
  __shared__ float Xs[32*129];
  const int tid = threadIdx.x;
  const int nbase = blockIdx.x * 32;
  for (int i = tid; i < 128*64/4; i += 256) {
    ((float4*)Ws)[i] = ((const float4*)W)[i];
    ((float4*)Rs)[i] = ((const float4*)RW)[i];
  }
  for (int idx = tid; idx < 32*32; idx += 256) {
    int node = idx >> 5, fq = idx & 31;
    int gn = nbase + node;
    float4 v = (gn < n) ? ((const float4*)X)[(size_t)gn*32 + fq] : float4{0.f,0.f,0.f,0.f};
    Xs[node*129 + fq*4 + 0] = v.x;
    Xs[node*129 + fq*4 + 1] = v.y;
    Xs[node*129 + fq*4 + 2] = v.z;
    Xs[node*129 + fq*4 + 3] = v.w;
  }
  __syncthreads();
  const int c0 = (tid & 15) * 4;
  const int n0 = (tid >> 4) * 2;
  float a0[4]={0,0,0,0}, a1[4]={0,0,0,0}, r0v[4]={0,0,0,0}, r1v[4]={0,0,0,0};
  #pragma unroll 4
  for (int k = 0; k < 128; k++) {
    float4 w  = *(const float4*)&Ws[k*64 + c0];
    float4 rw = *(const float4*)&Rs[k*64 + c0];
    float x0 = Xs[n0*129 + k];
    float x1 = Xs[n0*129 + 129 + k];
    a0[0]=fmaf(x0,w.x,a0[0]);  a0[1]=fmaf(x0,w.y,a0[1]);  a0[2]=fmaf(x0,w.z,a0[2]);  a0[3]=fmaf(x0,w.w,a0[3]);
    a1[0]=fmaf(x1,w.x,a1[0]);  a1[1]=fmaf(x1,w.y,a1[1]);  a1[2]=fmaf(x1,w.z,a1[2]);  a1[3]=fmaf(x1,w.w,a1[3]);
    r0v[0]=fmaf(x0,rw.x,r0v[0]); r0v[1]=fmaf(x0,rw.y,r0v[1]); r0v[2]=fmaf(x0,rw.z,r0v[2]); r0v[3]=fmaf(x0,rw.w,r0v[3]);
    r1v[0]=fmaf(x1,rw.x,r1v[0]); r1v[1]=fmaf(x1,rw.y,r1v[1]); r1v[2]=fmaf(x1,rw.z,r1v[2]); r1v[3]=fmaf(x1,rw.w,r1v[3]);
  }
  const int g0 = nbase + n0, g1 = g0 + 1;
  const int hh = c0 >> 4, cb = c0 & 15;
  if (g0 < n) {
    *(ushort4*)&featH[((size_t)hh*N + g0)*16 + cb] = ushort4{bf16bits(a0[0]),bf16bits(a0[1]),bf16bits(a0[2]),bf16bits(a0[3])};
    *(float4*)&res[(size_t)g0*64 + c0] = float4{r0v[0],r0v[1],r0v[2],r0v[3]};
  }
  if (g1 < n) {
    *(ushort4*)&featH[((size_t)hh*N + g1)*16 + cb] = ushort4{bf16bits(a1[0]),bf16bits(a1[1]),bf16bits(a1[2]),bf16bits(a1[3])};
    *(float4*)&res[(size_t)g1*64 + c0] = float4{r1v[0],r1v[1],r1v[2],r1v[3]};
  }
  float l0=al[c0], l1=al[c0+1], l2=al[c0+2], l3=al[c0+3];
  float q0=ar[c0], q1=ar[c0+1], q2=ar[c0+2], q3=ar[c0+3];
  float e0 = a0[0]*l0 + a0[1]*l1 + a0[2]*l2 + a0[3]*l3;
  float e1 = a1[0]*l0 + a1[1]*l1 + a1[2]*l2 + a1[3]*l3;
  float u0 = a0[0]*q0 + a0[1]*q1 + a0[2]*q2 + a0[3]*q3;
  float u1 = a1[0]*q0 + a1[1]*q1 + a1[2]*q2 + a1[3]*q3;
  e0 += __shfl_xor(e0,1); e0 += __shfl_xor(e0,2);
  e1 += __shfl_xor(e1,1); e1 += __shfl_xor(e1,2);
  u0 += __shfl_xor(u0,1); u0 += __shfl_xor(u0,2);
  u1 += __shfl_xor(u1,1); u1 += __shfl_xor(u1,2);
  if ((tid & 3) == 0) {
    int h = (tid & 15) >> 2;
    if (g0 < n) { el[g0*4+h] = e0; er[g0*4+h] = u0; }
    if (g1 < n) { el[g1*4+h] = e1; er[g1*4+h] = u1; }
  }
}

// ---------------- node linear, K=64: bf16 head-major out ----------------

__global__ __launch_bounds__(256) void lin64(const float* __restrict__ X,
    const float* __restrict__ W, const float* __restrict__ al, const float* __restrict__ ar,
    unsigned short* __restrict__ featH, float* __restrict__ el, float* __restrict__ er,
    int n, int N)
{
  __shared__ float Ws[64*64];
  __shared__ float Xs[64*65];
  const int tid = threadIdx.x;
  const int nbase = blockIdx.x * 64;
  for (int i = tid; i < 64*64/4; i += 256) ((float4*)Ws)[i] = ((const float4*)W)[i];
  for (int idx = tid; idx < 64*16; idx += 256) {
    int node = idx >> 4, fq = idx & 15;
    int gn = nbase + node;
    float4 v = (gn < n) ? ((const float4*)X)[(size_t)gn*16 + fq] : float4{0.f,0.f,0.f,0.f};
    Xs[node*65 + fq*4 + 0] = v.x;
    Xs[node*65 + fq*4 + 1] = v.y;
    Xs[node*65 + fq*4 + 2] = v.z;
    Xs[node*65 + fq*4 + 3] = v.w;
  }
  __syncthreads();
  const int c0 = (tid & 15) * 4;
  const int n0 = (tid >> 4) * 4;
  float acc[4][4];
  #pragma unroll
  for (int i = 0; i < 4; i++)
    #pragma unroll
    for (int j = 0; j < 4; j++) acc[i][j] = 0.f;
  #pragma unroll 4
  for (int k = 0; k < 64; k++) {
    float4 w = *(const float4*)&Ws[k*64 + c0];
    #pragma unroll
    for (int i = 0; i < 4; i++) {
      float x = Xs[(n0+i)*65 + k];
      acc[i][0] = fmaf(x, w.x, acc[i][0]);
      acc[i][1] = fmaf(x, w.y, acc[i][1]);
      acc[i][2] = fmaf(x, w.z, acc[i][2]);
      acc[i][3] = fmaf(x, w.w, acc[i][3]);
    }
  }
  float l0=al[c0], l1=al[c0+1], l2=al[c0+2], l3=al[c0+3];
  float r0=ar[c0], r1=ar[c0+1], r2=ar[c0+2], r3=ar[c0+3];
  const int hh = c0 >> 4, cb = c0 & 15;
  #pragma unroll
  for (int i = 0; i < 4; i++) {
    int g = nbase + n0 + i;
    if (g < n) *(ushort4*)&featH[((size_t)hh*N + g)*16 + cb] =
        ushort4{bf16bits(acc[i][0]),bf16bits(acc[i][1]),bf16bits(acc[i][2]),bf16bits(acc[i][3])};
    float e = acc[i][0]*l0 + acc[i][1]*l1 + acc[i][2]*l2 + acc[i][3]*l3;
    float q = acc[i][0]*r0 + acc[i][1]*r1 + acc[i][2]*r2 + acc[i][3]*r3;
    e += __shfl_xor(e,1); e += __shfl_xor(e,2);
    q += __shfl_xor(q,1); q += __shfl_xor(q,2);
    if ((tid & 3) == 0 && g < n) {
      int h = (tid & 15) >> 2;
      el[g*4+h] = e; er[g*4+h] = q;
    }
  }
}

// ------- edge-parallel scores -> head-major alphaH[h][e] (coalesced per head) -------

__global__ __launch_bounds__(256) void score_kernel(const int2* __restrict__ csr,
    const float* __restrict__ el, const float* __restrict__ er,
    float* __restrict__ alphaH, int E)
{
  int e = blockIdx.x*256 + threadIdx.x;
  if (e >= E) return;
  int2 sd = csr[e];
  float4 l = *(const float4*)&el[sd.x*4];
  float4 r = *(const float4*)&er[sd.y*4];
  alphaH[(size_t)0*E + e] = __expf(LEAKY(l.x + r.x));
  alphaH[(size_t)1*E + e] = __expf(LEAKY(l.y + r.y));
  alphaH[(size_t)2*E + e] = __expf(LEAKY(l.z + r.z));
  alphaH[(size_t)3*E + e] = __expf(LEAKY(l.w + r.w));
}

// ------------- head-split, XCD-pinned aggregation -------------
// block: slot=b&7 -> head=slot&3 (XCD b%8 sees ONE 3.2MB head table -> L2-resident).
// wave = one (node,head); lane = eg*16+d: 4 edges x 16 cols per iteration.

template<int LAYER>
__global__ __launch_bounds__(256) void aggregateH(const int* __restrict__ off,
    const int2* __restrict__ csr, const float* __restrict__ alphaH,
    const __hip_bfloat16* __restrict__ featH, const float* __restrict__ res,
    const float* __restrict__ bias, float* __restrict__ outp, int n, int N, int E)
{
  const int wave = threadIdx.x >> 6, lane = threadIdx.x & 63;
  const int slot = blockIdx.x & 7;
  const int h    = slot & 3;
  const int j    = blockIdx.x >> 3;
  const int node = (j*2 + (slot>>2))*4 + wave;
  if (node >= n) return;
  const int eg = lane >> 4, d = lane & 15;
  const int beg = off[node], end = off[node+1];
  const __hip_bfloat16* ft = featH + (size_t)h*N*16;
  const float* ap = alphaH + (size_t)h*E;
  float acc0=0.f, den0=0.f, acc1=0.f, den1=0.f;
  int i = beg;
  for (; i + 8 <= end; i += 8) {
    int   s0 = csr[i+eg].x,   s1 = csr[i+4+eg].x;
    float p0 = ap[i+eg],      p1 = ap[i+4+eg];
    float f0 = __bfloat162float(ft[(size_t)s0*16 + d]);
    float f1 = __bfloat162float(ft[(size_t)s1*16 + d]);
    den0 += p0; acc0 = fmaf(p0, f0, acc0);
    den1 += p1; acc1 = fmaf(p1, f1, acc1);
  }
  for (; i < end; i += 4) {
    bool act = (i + eg) < end;
    int   s = act ? csr[i+eg].x : 0;
    float p = act ? ap[i+eg] : 0.f;
    float f = __bfloat162float(ft[(size_t)s*16 + d]);
    den0 += p; acc0 = fmaf(p, f, acc0);
  }
  float acc = acc0 + acc1, den = den0 + den1;
  acc += __shfl_xor(acc,16); acc += __shfl_xor(acc,32);
  den += __shfl_xor(den,16); den += __shfl_xor(den,32);
  float v = (den > 0.f) ? (acc/den) : 0.f;
  const int c = h*16 + d;
  v += res[(size_t)node*64 + c] + bias[c];
  if (LAYER == 1) {
    v = (v > 0.f) ? v : expm1f(v);                      // elu
    if (eg == 0) outp[(size_t)node*64 + c] = v;         // hbuf, node-major
  } else {
    if (eg == 0) outp[((size_t)h*N + node)*16 + d] = v; // per-head partial
  }
}

// ---------------- combine: out[n,d] = 0.25 * sum_h outH[h][n][d] ----------------

__global__ __launch_bounds__(256) void combine_kernel(const float* __restrict__ outH,
    float* __restrict__ out, int n, int N)
{
  int t = blockIdx.x*256 + threadIdx.x;       // one thread = 4 cols
  if (t >= n*4) return;
  int node = t >> 2, q = t & 3;
  float4 s{0.f,0.f,0.f,0.f};
  #pragma unroll
  for (int h = 0; h < 4; h++) {
    float4 v = ((const float4*)(outH + ((size_t)h*N + node)*16))[q];
    s.x += v.x; s.y += v.y; s.z += v.z; s.w += v.w;
  }
  ((float4*)(out + (size_t)node*16))[q] = float4{0.25f*s.x, 0.25f*s.y, 0.25f*s.z, 0.25f*s.w};
}

// ---------------- launch ----------------

extern "C" void kernel_launch(void* const* d_in, const int* in_sizes, int n_in,
                              void* d_out, int out_size, void* d_ws, size_t ws_size,
                              hipStream_t stream)
{
  (void)n_in; (void)out_size; (void)ws_size;
  const float* x   = (const float*)d_in[0];
  const int*   src = (const int*)  d_in[1];
  const int*   dst = (const int*)  d_in[2];
  const float* W1  = (const float*)d_in[3];
  const float* al1 = (const float*)d_in[4];
  const float* ar1 = (const float*)d_in[5];
  const float* rW1 = (const float*)d_in[6];
  const float* b1  = (const float*)d_in[7];
  const float* W2  = (const float*)d_in[8];
  const float* al2 = (const float*)d_in[9];
  const float* ar2 = (const float*)d_in[10];
  const float* b2  = (const float*)d_in[11];
  float* out = (float*)d_out;

  const int N_ = in_sizes[0] / 128;   // 100000
  const int E_ = in_sizes[1];         // 1600000
  const int B_ = cdiv(N_, NBK);       // 391 buckets (<=512 required)

  char* ws = (char*)d_ws;
  size_t o = 0;
  auto alloc = [&](size_t bytes)->char* {
    char* p = ws + o; o += (bytes + 255) & ~(size_t)255; return p;
  };
  int*   acur    = (int*)  alloc((size_t)B_*4);
  int*   bbase   = (int*)  alloc(((size_t)B_+1)*4);
  int*   off     = (int*)  alloc(((size_t)N_+1)*4);
  unsigned int* tmp = (unsigned int*)alloc((size_t)B_*CAP*4);
  int2*  csr     = (int2*) alloc((size_t)E_*8);
  float* alphaH  = (float*)alloc((size_t)E_*4*4);
  unsigned short* featH = (unsigned short*)alloc((size_t)N_*64*2);  // bf16 head-major
  float* el      = (float*)alloc((size_t)N_*4*4);
  float* er      = (float*)alloc((size_t)N_*4*4);
  float* hbuf    = (float*)alloc((size_t)N_*64*4);   // res1 -> layer-1 out (layer-2 in/res)
  float* outH    = (float*)alloc((size_t)N_*64*4);   // layer-2 per-head partials

  // CSR build (rebuilt every call — no static state)
  hipMemsetAsync(acur, 0, (size_t)B_*4, stream);
  binA<<<128, 256, 0, stream>>>(src, dst, acur, tmp, E_, B_, cdiv(E_,128));
  bucket_scan<<<1, 512, 0, stream>>>(acur, bbase, off, B_, N_, E_);
  binC<<<B_, 256, 0, stream>>>(tmp, acur, bbase, off, csr, N_);

  const int aggGrid = 8 * cdiv(N_, 8);

  // ---- layer 1 ----
  lin128_fused<<<cdiv(N_,32), 256, 0, stream>>>(x, W1, rW1, al1, ar1, featH, el, er, hbuf, N_, N_);
  score_kernel<<<cdiv(E_,256), 256, 0, stream>>>(csr, el, er, alphaH, E_);
  aggregateH<1><<<aggGrid, 256, 0, stream>>>(off, csr, alphaH,
      (const __hip_bfloat16*)featH, hbuf, b1, hbuf, N_, N_, E_);

  // ---- layer 2 ----
  lin64<<<cdiv(N_,64), 256, 0, stream>>>(hbuf, W2, al2, ar2, featH, el, er, N_, N_);
  score_kernel<<<cdiv(E_,256), 256, 0, stream>>>(csr, el, er, alphaH, E_);
  aggregateH<2><<<aggGrid, 256, 0, stream>>>(off, csr, alphaH,
      (const __hip_bfloat16*)featH, hbuf, b2, outH, N_, N_, E_);
  combine_kernel<<<cdiv(N_*4,256), 256, 0, stream>>>(outH, out, N_, N_);
}

// Round 9
// 406.774 us; speedup vs baseline: 1.5884x; 1.5884x over previous
//
#include <hip/hip_runtime.h>
#include <hip/hip_bf16.h>

static inline int cdiv(int a, int b){ return (a+b-1)/b; }

#define LEAKY(x) ((x) >= 0.f ? (x) : 0.2f*(x))

#define NBK   256          // nodes per dst-bucket
#define NBKSH 8
#define CAP   5120         // tmp slots per bucket (mean 4096, ~16 sigma margin)
#define SCAP  1024         // staged alpha slots per aggregate block (4 nodes, mean 64)

__device__ inline unsigned short bf16bits(float f){
  __hip_bfloat16 h = __float2bfloat16(f);
  return *reinterpret_cast<unsigned short*>(&h);
}

// ---------------- CSR build, phase A: bin edges by dst bucket ----------------

__global__ __launch_bounds__(256) void binA(const int* __restrict__ src,
    const int* __restrict__ dst, int* __restrict__ acur, unsigned int* __restrict__ tmp,
    int E, int B, int epb)
{
  __shared__ int cnt1[512], cnt2[512], gbase[512];
  const int tid = threadIdx.x;
  for (int j = tid; j < 512; j += 256) { cnt1[j] = 0; cnt2[j] = 0; }
  __syncthreads();
  const int beg = blockIdx.x*epb, end = min(E, beg+epb);
  for (int e = beg+tid; e < end; e += 256) atomicAdd(&cnt1[dst[e]>>NBKSH], 1);
  __syncthreads();
  for (int j = tid; j < B; j += 256) gbase[j] = atomicAdd(&acur[j], cnt1[j]);
  __syncthreads();
  for (int e = beg+tid; e < end; e += 256) {
    int s = src[e], d = dst[e];
    int b = d >> NBKSH;
    int tk = atomicAdd(&cnt2[b], 1);
    int slot = gbase[b] + tk;
    if (slot < CAP)                     // safety; never hit for this graph
      tmp[(size_t)b*CAP + slot] = ((unsigned)s << NBKSH) | (unsigned)(d & (NBK-1));
  }
}

// ---------------- phase B: scan bucket counts -> bucket bases; off[N]=E ----------------

__global__ __launch_bounds__(512) void bucket_scan(const int* __restrict__ acur,
    int* __restrict__ bbase, int* __restrict__ off, int B, int N, int E)
{
  __shared__ int wsum[8];
  const int tid = threadIdx.x, lane = tid & 63, wave = tid >> 6;
  int v = (tid < B) ? acur[tid] : 0;
  int x = v;
  #pragma unroll
  for (int s = 1; s < 64; s <<= 1) { int t = __shfl_up(x, s); if (lane >= s) x += t; }
  if (lane == 63) wsum[wave] = x;
  __syncthreads();
  if (tid == 0) { int r = 0; for (int w = 0; w < 8; w++) { int t = wsum[w]; wsum[w] = r; r += t; } }
  __syncthreads();
  int excl = wsum[wave] + x - v;
  if (tid < B)    bbase[tid] = excl;
  if (tid == B-1) bbase[B]   = excl + v;
  if (tid == 0)   off[N]     = E;
}

// ---------------- phase C: per-bucket local CSR (one block per bucket) ----------------

__global__ __launch_bounds__(256) void binC(const unsigned int* __restrict__ tmp,
    const int* __restrict__ acur, const int* __restrict__ bbase,
    int* __restrict__ off, int* __restrict__ csr_src, int N)
{
  __shared__ int sA[NBK], sB[NBK];
  const int b = blockIdx.x, tid = threadIdx.x;
  const int m = min(acur[b], CAP);
  const int base = bbase[b];
  const int n0 = b*NBK;
  const int nn = min(NBK, N - n0);
  if (tid < NBK) sA[tid] = 0;
  __syncthreads();
  const unsigned int* tb = tmp + (size_t)b*CAP;
  for (int i = tid; i < m; i += 256) atomicAdd(&sA[tb[i] & (NBK-1)], 1);
  __syncthreads();
  int* in = sA; int* ob = sB;
  for (int st = 1; st < NBK; st <<= 1) {
    if (tid < NBK) { int v = in[tid]; if (tid >= st) v += in[tid-st]; ob[tid] = v; }
    __syncthreads();
    int* t = in; in = ob; ob = t;
  }
  if (tid < NBK) ob[tid] = tid ? in[tid-1] : 0;   // exclusive into ob
  __syncthreads();
  if (tid < nn) off[n0 + tid] = base + ob[tid];
  __syncthreads();
  for (int i = tid; i < m; i += 256) {       // ob doubles as per-node cursor
    unsigned v = tb[i];
    int pos = atomicAdd(&ob[v & (NBK-1)], 1);
    csr_src[base + pos] = (int)(v >> NBKSH);
  }
}

// -------- node linear K=128, X staged ONCE, W1 then resW1 sequentially --------
// 32-node tile; thread t: cols c0=(t&15)*4..+3, nodes n0=(t>>4)*2..+1.
// LDS = 32KB (W buffer, reused) + 16.5KB (X) -> 3 blocks/CU.

__global__ __launch_bounds__(256) void lin128_once(const float* __restrict__ X,
    const float* __restrict__ W, const float* __restrict__ RW,
    const float* __restrict__ al, const float* __restrict__ ar,
    unsigned short* __restrict__ featb, float* __restrict__ el, float* __restrict__ er,
    float* __restrict__ res, int n)
{
  __shared__ float Ws[128*64];
  __shared__ float Xs[32*129];
  const int tid = threadIdx.x;
  const int nbase = blockIdx.x * 32;
  for (int i = tid; i < 128*64/4; i += 256) ((float4*)Ws)[i] = ((const float4*)W)[i];
  for (int idx = tid; idx < 32*32; idx += 256) {
    int node = idx >> 5, fq = idx & 31;
    int gn = nbase + node;
    float4 v = (gn < n) ? ((const float4*)X)[(size_t)gn*32 + fq] : float4{0.f,0.f,0.f,0.f};
    Xs[node*129 + fq*4 + 0] = v.x;
    Xs[node*129 + fq*4 + 1] = v.y;
    Xs[node*129 + fq*4 + 2] = v.z;
    Xs[node*129 + fq*4 + 3] = v.w;
  }
  __syncthreads();
  const int c0 = (tid & 15) * 4;
  const int n0 = (tid >> 4) * 2;
  const int g0 = nbase + n0, g1 = g0 + 1;
  {
    float a00=0,a01=0,a02=0,a03=0, a10=0,a11=0,a12=0,a13=0;
    #pragma unroll 4
    for (int k = 0; k < 128; k++) {
      float4 w = *(const float4*)&Ws[k*64 + c0];
      float x0 = Xs[n0*129 + k];
      float x1 = Xs[n0*129 + 129 + k];
      a00 = fmaf(x0, w.x, a00); a01 = fmaf(x0, w.y, a01);
      a02 = fmaf(x0, w.z, a02); a03 = fmaf(x0, w.w, a03);
      a10 = fmaf(x1, w.x, a10); a11 = fmaf(x1, w.y, a11);
      a12 = fmaf(x1, w.z, a12); a13 = fmaf(x1, w.w, a13);
    }
    if (g0 < n) *(ushort4*)&featb[(size_t)g0*64 + c0] = ushort4{bf16bits(a00),bf16bits(a01),bf16bits(a02),bf16bits(a03)};
    if (g1 < n) *(ushort4*)&featb[(size_t)g1*64 + c0] = ushort4{bf16bits(a10),bf16bits(a11),bf16bits(a12),bf16bits(a13)};
    float l0=al[c0], l1=al[c0+1], l2=al[c0+2], l3=al[c0+3];
    float r0=ar[c0], r1=ar[c0+1], r2=ar[c0+2], r3=ar[c0+3];
    float e0 = a00*l0 + a01*l1 + a02*l2 + a03*l3;
    float e1 = a10*l0 + a11*l1 + a12*l2 + a13*l3;
    float q0 = a00*r0 + a01*r1 + a02*r2 + a03*r3;
    float q1 = a10*r0 + a11*r1 + a12*r2 + a13*r3;
    e0 += __shfl_xor(e0,1); e0 += __shfl_xor(e0,2);
    e1 += __shfl_xor(e1,1); e1 += __shfl_xor(e1,2);
    q0 += __shfl_xor(q0,1); q0 += __shfl_xor(q0,2);
    q1 += __shfl_xor(q1,1); q1 += __shfl_xor(q1,2);
    if ((tid & 3) == 0) {
      int h = (tid & 15) >> 2;
      if (g0 < n) { el[g0*4+h] = e0; er[g0*4+h] = q0; }
      if (g1 < n) { el[g1*4+h] = e1; er[g1*4+h] = q1; }
    }
  }
  __syncthreads();   // all waves done reading Ws (pass 1)
  for (int i = tid; i < 128*64/4; i += 256) ((float4*)Ws)[i] = ((const float4*)RW)[i];
  __syncthreads();
  {
    float a00=0,a01=0,a02=0,a03=0, a10=0,a11=0,a12=0,a13=0;
    #pragma unroll 4
    for (int k = 0; k < 128; k++) {
      float4 w = *(const float4*)&Ws[k*64 + c0];
      float x0 = Xs[n0*129 + k];
      float x1 = Xs[n0*129 + 129 + k];
      a00 = fmaf(x0, w.x, a00); a01 = fmaf(x0, w.y, a01);
      a02 = fmaf(x0, w.z, a02); a03 = fmaf(x0, w.w, a03);
      a10 = fmaf(x1, w.x, a10); a11 = fmaf(x1, w.y, a11);
      a12 = fmaf(x1, w.z, a12); a13 = fmaf(x1, w.w, a13);
    }
    if (g0 < n) *(float4*)&res[(size_t)g0*64 + c0] = float4{a00,a01,a02,a03};
    if (g1 < n) *(float4*)&res[(size_t)g1*64 + c0] = float4{a10,a11,a12,a13};
  }
}

// ---------------- node linear, K=64: 64-node tile, 4x4 microtile, bf16 out ----------------

__global__ __launch_bounds__(256) void lin64(const float* __restrict__ X,
    const float* __restrict__ W, const float* __restrict__ al, const float* __restrict__ ar,
    unsigned short* __restrict__ feat, float* __restrict__ el, float* __restrict__ er, int n)
{
  __shared__ float Ws[64*64];
  __shared__ float Xs[64*65];
  const int tid = threadIdx.x;
  const int nbase = blockIdx.x * 64;
  for (int i = tid; i < 64*64/4; i += 256) ((float4*)Ws)[i] = ((const float4*)W)[i];
  for (int idx = tid; idx < 64*16; idx += 256) {
    int node = idx >> 4, fq = idx & 15;
    int gn = nbase + node;
    float4 v = (gn < n) ? ((const float4*)X)[(size_t)gn*16 + fq] : float4{0.f,0.f,0.f,0.f};
    Xs[node*65 + fq*4 + 0] = v.x;
    Xs[node*65 + fq*4 + 1] = v.y;
    Xs[node*65 + fq*4 + 2] = v.z;
    Xs[node*65 + fq*4 + 3] = v.w;
  }
  __syncthreads();
  const int c0 = (tid & 15) * 4;
  const int n0 = (tid >> 4) * 4;
  float acc[4][4];
  #pragma unroll
  for (int i = 0; i < 4; i++)
    #pragma unroll
    for (int j = 0; j < 4; j++) acc[i][j] = 0.f;
  #pragma unroll 4
  for (int k = 0; k < 64; k++) {
    float4 w = *(const float4*)&Ws[k*64 + c0];
    #pragma unroll
    for (int i = 0; i < 4; i++) {
      float x = Xs[(n0+i)*65 + k];
      acc[i][0] = fmaf(x, w.x, acc[i][0]);
      acc[i][1] = fmaf(x, w.y, acc[i][1]);
      acc[i][2] = fmaf(x, w.z, acc[i][2]);
      acc[i][3] = fmaf(x, w.w, acc[i][3]);
    }
  }
  float l0=al[c0], l1=al[c0+1], l2=al[c0+2], l3=al[c0+3];
  float r0=ar[c0], r1=ar[c0+1], r2=ar[c0+2], r3=ar[c0+3];
  #pragma unroll
  for (int i = 0; i < 4; i++) {
    int g = nbase + n0 + i;
    if (g < n) *(ushort4*)&feat[(size_t)g*64 + c0] =
        ushort4{bf16bits(acc[i][0]),bf16bits(acc[i][1]),bf16bits(acc[i][2]),bf16bits(acc[i][3])};
    float e = acc[i][0]*l0 + acc[i][1]*l1 + acc[i][2]*l2 + acc[i][3]*l3;
    float q = acc[i][0]*r0 + acc[i][1]*r1 + acc[i][2]*r2 + acc[i][3]*r3;
    e += __shfl_xor(e,1); e += __shfl_xor(e,2);
    q += __shfl_xor(q,1); q += __shfl_xor(q,2);
    if ((tid & 3) == 0 && g < n) {
      int h = (tid & 15) >> 2;
      el[g*4+h] = e; er[g*4+h] = q;
    }
  }
}

// ------- fused score-staging + softmax + aggregation + epilogue -------
// Block = 4 nodes. Stage alpha=exp(leaky(el[src]+er[dst])) for the block's OWN
// contiguous edge range into LDS (one exp per edge-head), then each wave does a
// pure gather+fma loop reading alpha from LDS. dst derived from off[] (3 cmps).

template<int LAYER>
__global__ __launch_bounds__(256) void aggregate_fused(const int* __restrict__ off,
    const int* __restrict__ csr_src, const float* __restrict__ el, const float* __restrict__ er,
    const __hip_bfloat16* __restrict__ feat, const float* __restrict__ res,
    const float* __restrict__ bias, float* __restrict__ out, int n)
{
  __shared__ float sp[SCAP*4];     // 16KB staged alpha
  __shared__ float er_s[4][4];
  __shared__ int   so[5];
  const int tid = threadIdx.x, wave = tid >> 6, lane = tid & 63;
  const int nb = blockIdx.x*4;
  if (tid < 5) so[tid] = off[min(nb + tid, n)];
  if (tid >= 5 && tid < 21) {
    int t = tid - 5;                   // t = node*4+h over 16
    int g = nb + (t >> 2);
    er_s[t >> 2][t & 3] = (g < n) ? er[g*4 + (t & 3)] : 0.f;
  }
  __syncthreads();
  const int b0 = so[0], b4 = so[4];
  const int cnt = b4 - b0;
  const bool staged = cnt <= SCAP;
  if (staged) {
    const int o1 = so[1], o2 = so[2], o3 = so[3];
    for (int j = b0 + tid; j < b4; j += 256) {
      int s = csr_src[j];
      int t = (j >= o1) + (j >= o2) + (j >= o3);
      float4 l = *(const float4*)&el[s*4];
      int li = j - b0;
      sp[li*4+0] = __expf(LEAKY(l.x + er_s[t][0]));
      sp[li*4+1] = __expf(LEAKY(l.y + er_s[t][1]));
      sp[li*4+2] = __expf(LEAKY(l.z + er_s[t][2]));
      sp[li*4+3] = __expf(LEAKY(l.w + er_s[t][3]));
    }
  }
  __syncthreads();
  const int node = nb + wave;
  if (node >= n) return;
  const int h = lane >> 4;
  const int beg = so[wave], end = so[wave+1];
  float d[8], a[8];
  #pragma unroll
  for (int k = 0; k < 8; k++) { d[k] = 0.f; a[k] = 0.f; }
  int i = beg;
  if (staged) {
    for (; i + 8 <= end; i += 8) {
      int   s[8]; float p[8], f[8];
      #pragma unroll
      for (int k = 0; k < 8; k++) s[k] = csr_src[i+k];
      #pragma unroll
      for (int k = 0; k < 8; k++) p[k] = sp[(i+k-b0)*4 + h];
      #pragma unroll
      for (int k = 0; k < 8; k++) f[k] = __bfloat162float(feat[(size_t)s[k]*64 + lane]);
      #pragma unroll
      for (int k = 0; k < 8; k++) { d[k] += p[k]; a[k] = fmaf(p[k], f[k], a[k]); }
    }
    for (; i < end; i++) {
      int s = csr_src[i];
      float p = sp[(i-b0)*4 + h];
      d[0] += p;
      a[0] = fmaf(p, __bfloat162float(feat[(size_t)s*64 + lane]), a[0]);
    }
  } else {                                   // fallback (never for this graph)
    const float erh = er_s[wave][h];
    for (; i < end; i++) {
      int s = csr_src[i];
      float p = __expf(LEAKY(el[s*4 + h] + erh));
      d[0] += p;
      a[0] = fmaf(p, __bfloat162float(feat[(size_t)s*64 + lane]), a[0]);
    }
  }
  float den = ((d[0]+d[1])+(d[2]+d[3])) + ((d[4]+d[5])+(d[6]+d[7]));
  float acc = ((a[0]+a[1])+(a[2]+a[3])) + ((a[4]+a[5])+(a[6]+a[7]));
  float v = (den > 0.f) ? (acc/den) : 0.f;           // empty segment -> 0
  v += res[(size_t)node*64 + lane] + bias[lane];
  if (LAYER == 1) {
    v = (v > 0.f) ? v : expm1f(v);                   // elu
    out[(size_t)node*64 + lane] = v;
  } else {
    v += __shfl_xor(v, 16);                          // mean over 4 heads
    v += __shfl_xor(v, 32);
    if (lane < 16) out[(size_t)node*16 + lane] = 0.25f*v;
  }
}

// ---------------- launch ----------------

extern "C" void kernel_launch(void* const* d_in, const int* in_sizes, int n_in,
                              void* d_out, int out_size, void* d_ws, size_t ws_size,
                              hipStream_t stream)
{
  (void)n_in; (void)out_size; (void)ws_size;
  const float* x   = (const float*)d_in[0];
  const int*   src = (const int*)  d_in[1];
  const int*   dst = (const int*)  d_in[2];
  const float* W1  = (const float*)d_in[3];
  const float* al1 = (const float*)d_in[4];
  const float* ar1 = (const float*)d_in[5];
  const float* rW1 = (const float*)d_in[6];
  const float* b1  = (const float*)d_in[7];
  const float* W2  = (const float*)d_in[8];
  const float* al2 = (const float*)d_in[9];
  const float* ar2 = (const float*)d_in[10];
  const float* b2  = (const float*)d_in[11];
  float* out = (float*)d_out;

  const int N_ = in_sizes[0] / 128;   // 100000
  const int E_ = in_sizes[1];         // 1600000
  const int B_ = cdiv(N_, NBK);       // 391 buckets

  char* ws = (char*)d_ws;
  size_t o = 0;
  auto alloc = [&](size_t bytes)->char* {
    char* p = ws + o; o += (bytes + 255) & ~(size_t)255; return p;
  };
  int*   acur    = (int*)  alloc((size_t)B_*4);
  int*   bbase   = (int*)  alloc(((size_t)B_+1)*4);
  int*   off     = (int*)  alloc(((size_t)N_+1)*4);
  unsigned int* tmp = (unsigned int*)alloc((size_t)B_*CAP*4);
  int*   csr_src = (int*)  alloc((size_t)E_*4);
  unsigned short* featb = (unsigned short*)alloc((size_t)N_*64*2);  // bf16
  float* el      = (float*)alloc((size_t)N_*4*4);
  float* er      = (float*)alloc((size_t)N_*4*4);
  float* hbuf    = (float*)alloc((size_t)N_*64*4);   // res1 -> layer-1 out -> layer-2 res

  // CSR build (rebuilt every call — no static state)
  hipMemsetAsync(acur, 0, (size_t)B_*4, stream);
  binA<<<256, 256, 0, stream>>>(src, dst, acur, tmp, E_, B_, cdiv(E_,256));
  bucket_scan<<<1, 512, 0, stream>>>(acur, bbase, off, B_, N_, E_);
  binC<<<B_, 256, 0, stream>>>(tmp, acur, bbase, off, csr_src, N_);

  // ---- layer 1 ----
  lin128_once<<<cdiv(N_,32), 256, 0, stream>>>(x, W1, rW1, al1, ar1, featb, el, er, hbuf, N_);
  aggregate_fused<1><<<cdiv(N_,4), 256, 0, stream>>>(off, csr_src, el, er,
      (const __hip_bfloat16*)featb, hbuf, b1, hbuf, N_);

  // ---- layer 2 ----
  lin64<<<cdiv(N_,64), 256, 0, stream>>>(hbuf, W2, al2, ar2, featb, el, er, N_);
  aggregate_fused<2><<<cdiv(N_,4), 256, 0, stream>>>(off, csr_src, el, er,
      (const __hip_bfloat16*)featb, hbuf, b2, out, N_);
}

// Round 10
// 368.821 us; speedup vs baseline: 1.7519x; 1.1029x over previous
//
#include <hip/hip_runtime.h>
#include <hip/hip_bf16.h>

static inline int cdiv(int a, int b){ return (a+b-1)/b; }

#define LEAKY(x) ((x) >= 0.f ? (x) : 0.2f*(x))

#define NBK   256          // nodes per dst-bucket
#define NBKSH 8
#define CAP   5120         // tmp slots per bucket (mean 4096, ~16 sigma margin)
#define SCAP  512          // staged alpha slots per aggregate block (4 nodes, mean 64, max ~200)

__device__ inline unsigned short bf16bits(float f){
  __hip_bfloat16 h = __float2bfloat16(f);
  return *reinterpret_cast<unsigned short*>(&h);
}
__device__ inline float bf16lo(unsigned u){ return __uint_as_float(u << 16); }
__device__ inline float bf16hi(unsigned u){ return __uint_as_float(u & 0xffff0000u); }

// ---------------- CSR build, phase A: bin edges by dst bucket ----------------

__global__ __launch_bounds__(256) void binA(const int* __restrict__ src,
    const int* __restrict__ dst, int* __restrict__ acur, unsigned int* __restrict__ tmp,
    int E, int B, int epb)
{
  __shared__ int cnt1[512], cnt2[512], gbase[512];
  const int tid = threadIdx.x;
  for (int j = tid; j < 512; j += 256) { cnt1[j] = 0; cnt2[j] = 0; }
  __syncthreads();
  const int beg = blockIdx.x*epb, end = min(E, beg+epb);
  for (int e = beg+tid; e < end; e += 256) atomicAdd(&cnt1[dst[e]>>NBKSH], 1);
  __syncthreads();
  for (int j = tid; j < B; j += 256) gbase[j] = atomicAdd(&acur[j], cnt1[j]);
  __syncthreads();
  for (int e = beg+tid; e < end; e += 256) {
    int s = src[e], d = dst[e];
    int b = d >> NBKSH;
    int tk = atomicAdd(&cnt2[b], 1);
    int slot = gbase[b] + tk;
    if (slot < CAP)                     // safety; never hit for this graph
      tmp[(size_t)b*CAP + slot] = ((unsigned)s << NBKSH) | (unsigned)(d & (NBK-1));
  }
}

// ---------------- phase B: scan bucket counts -> bucket bases; off[N]=E ----------------

__global__ __launch_bounds__(512) void bucket_scan(const int* __restrict__ acur,
    int* __restrict__ bbase, int* __restrict__ off, int B, int N, int E)
{
  __shared__ int wsum[8];
  const int tid = threadIdx.x, lane = tid & 63, wave = tid >> 6;
  int v = (tid < B) ? acur[tid] : 0;
  int x = v;
  #pragma unroll
  for (int s = 1; s < 64; s <<= 1) { int t = __shfl_up(x, s); if (lane >= s) x += t; }
  if (lane == 63) wsum[wave] = x;
  __syncthreads();
  if (tid == 0) { int r = 0; for (int w = 0; w < 8; w++) { int t = wsum[w]; wsum[w] = r; r += t; } }
  __syncthreads();
  int excl = wsum[wave] + x - v;
  if (tid < B)    bbase[tid] = excl;
  if (tid == B-1) bbase[B]   = excl + v;
  if (tid == 0)   off[N]     = E;
}

// ---------------- phase C: per-bucket local CSR (one block per bucket) ----------------

__global__ __launch_bounds__(256) void binC(const unsigned int* __restrict__ tmp,
    const int* __restrict__ acur, const int* __restrict__ bbase,
    int* __restrict__ off, int* __restrict__ csr_src, int N)
{
  __shared__ int sA[NBK], sB[NBK];
  const int b = blockIdx.x, tid = threadIdx.x;
  const int m = min(acur[b], CAP);
  const int base = bbase[b];
  const int n0 = b*NBK;
  const int nn = min(NBK, N - n0);
  if (tid < NBK) sA[tid] = 0;
  __syncthreads();
  const unsigned int* tb = tmp + (size_t)b*CAP;
  for (int i = tid; i < m; i += 256) atomicAdd(&sA[tb[i] & (NBK-1)], 1);
  __syncthreads();
  int* in = sA; int* ob = sB;
  for (int st = 1; st < NBK; st <<= 1) {
    if (tid < NBK) { int v = in[tid]; if (tid >= st) v += in[tid-st]; ob[tid] = v; }
    __syncthreads();
    int* t = in; in = ob; ob = t;
  }
  if (tid < NBK) ob[tid] = tid ? in[tid-1] : 0;   // exclusive into ob
  __syncthreads();
  if (tid < nn) off[n0 + tid] = base + ob[tid];
  __syncthreads();
  for (int i = tid; i < m; i += 256) {       // ob doubles as per-node cursor
    unsigned v = tb[i];
    int pos = atomicAdd(&ob[v & (NBK-1)], 1);
    csr_src[base + pos] = (int)(v >> NBKSH);
  }
}

// -------- node linear K=128, X staged ONCE, W1 then resW1 sequentially --------

__global__ __launch_bounds__(256) void lin128_once(const float* __restrict__ X,
    const float* __restrict__ W, const float* __restrict__ RW,
    const float* __restrict__ al, const float* __restrict__ ar,
    unsigned short* __restrict__ featb, float* __restrict__ el, float* __restrict__ er,
    float* __restrict__ res, int n)
{
  __shared__ float Ws[128*64];
  __shared__ float Xs[32*129];
  const int tid = threadIdx.x;
  const int nbase = blockIdx.x * 32;
  for (int i = tid; i < 128*64/4; i += 256) ((float4*)Ws)[i] = ((const float4*)W)[i];
  for (int idx = tid; idx < 32*32; idx += 256) {
    int node = idx >> 5, fq = idx & 31;
    int gn = nbase + node;
    float4 v = (gn < n) ? ((const float4*)X)[(size_t)gn*32 + fq] : float4{0.f,0.f,0.f,0.f};
    Xs[node*129 + fq*4 + 0] = v.x;
    Xs[node*129 + fq*4 + 1] = v.y;
    Xs[node*129 + fq*4 + 2] = v.z;
    Xs[node*129 + fq*4 + 3] = v.w;
  }
  __syncthreads();
  const int c0 = (tid & 15) * 4;
  const int n0 = (tid >> 4) * 2;
  const int g0 = nbase + n0, g1 = g0 + 1;
  {
    float a00=0,a01=0,a02=0,a03=0, a10=0,a11=0,a12=0,a13=0;
    #pragma unroll 4
    for (int k = 0; k < 128; k++) {
      float4 w = *(const float4*)&Ws[k*64 + c0];
      float x0 = Xs[n0*129 + k];
      float x1 = Xs[n0*129 + 129 + k];
      a00 = fmaf(x0, w.x, a00); a01 = fmaf(x0, w.y, a01);
      a02 = fmaf(x0, w.z, a02); a03 = fmaf(x0, w.w, a03);
      a10 = fmaf(x1, w.x, a10); a11 = fmaf(x1, w.y, a11);
      a12 = fmaf(x1, w.z, a12); a13 = fmaf(x1, w.w, a13);
    }
    if (g0 < n) *(ushort4*)&featb[(size_t)g0*64 + c0] = ushort4{bf16bits(a00),bf16bits(a01),bf16bits(a02),bf16bits(a03)};
    if (g1 < n) *(ushort4*)&featb[(size_t)g1*64 + c0] = ushort4{bf16bits(a10),bf16bits(a11),bf16bits(a12),bf16bits(a13)};
    float l0=al[c0], l1=al[c0+1], l2=al[c0+2], l3=al[c0+3];
    float r0=ar[c0], r1=ar[c0+1], r2=ar[c0+2], r3=ar[c0+3];
    float e0 = a00*l0 + a01*l1 + a02*l2 + a03*l3;
    float e1 = a10*l0 + a11*l1 + a12*l2 + a13*l3;
    float q0 = a00*r0 + a01*r1 + a02*r2 + a03*r3;
    float q1 = a10*r0 + a11*r1 + a12*r2 + a13*r3;
    e0 += __shfl_xor(e0,1); e0 += __shfl_xor(e0,2);
    e1 += __shfl_xor(e1,1); e1 += __shfl_xor(e1,2);
    q0 += __shfl_xor(q0,1); q0 += __shfl_xor(q0,2);
    q1 += __shfl_xor(q1,1); q1 += __shfl_xor(q1,2);
    if ((tid & 3) == 0) {
      int h = (tid & 15) >> 2;
      if (g0 < n) { el[g0*4+h] = e0; er[g0*4+h] = q0; }
      if (g1 < n) { el[g1*4+h] = e1; er[g1*4+h] = q1; }
    }
  }
  __syncthreads();   // all waves done reading Ws (pass 1)
  for (int i = tid; i < 128*64/4; i += 256) ((float4*)Ws)[i] = ((const float4*)RW)[i];
  __syncthreads();
  {
    float a00=0,a01=0,a02=0,a03=0, a10=0,a11=0,a12=0,a13=0;
    #pragma unroll 4
    for (int k = 0; k < 128; k++) {
      float4 w = *(const float4*)&Ws[k*64 + c0];
      float x0 = Xs[n0*129 + k];
      float x1 = Xs[n0*129 + 129 + k];
      a00 = fmaf(x0, w.x, a00); a01 = fmaf(x0, w.y, a01);
      a02 = fmaf(x0, w.z, a02); a03 = fmaf(x0, w.w, a03);
      a10 = fmaf(x1, w.x, a10); a11 = fmaf(x1, w.y, a11);
      a12 = fmaf(x1, w.z, a12); a13 = fmaf(x1, w.w, a13);
    }
    if (g0 < n) *(float4*)&res[(size_t)g0*64 + c0] = float4{a00,a01,a02,a03};
    if (g1 < n) *(float4*)&res[(size_t)g1*64 + c0] = float4{a10,a11,a12,a13};
  }
}

// ---------------- node linear, K=64: 64-node tile, 4x4 microtile, bf16 out ----------------

__global__ __launch_bounds__(256) void lin64(const float* __restrict__ X,
    const float* __restrict__ W, const float* __restrict__ al, const float* __restrict__ ar,
    unsigned short* __restrict__ feat, float* __restrict__ el, float* __restrict__ er, int n)
{
  __shared__ float Ws[64*64];
  __shared__ float Xs[64*65];
  const int tid = threadIdx.x;
  const int nbase = blockIdx.x * 64;
  for (int i = tid; i < 64*64/4; i += 256) ((float4*)Ws)[i] = ((const float4*)W)[i];
  for (int idx = tid; idx < 64*16; idx += 256) {
    int node = idx >> 4, fq = idx & 15;
    int gn = nbase + node;
    float4 v = (gn < n) ? ((const float4*)X)[(size_t)gn*16 + fq] : float4{0.f,0.f,0.f,0.f};
    Xs[node*65 + fq*4 + 0] = v.x;
    Xs[node*65 + fq*4 + 1] = v.y;
    Xs[node*65 + fq*4 + 2] = v.z;
    Xs[node*65 + fq*4 + 3] = v.w;
  }
  __syncthreads();
  const int c0 = (tid & 15) * 4;
  const int n0 = (tid >> 4) * 4;
  float acc[4][4];
  #pragma unroll
  for (int i = 0; i < 4; i++)
    #pragma unroll
    for (int j = 0; j < 4; j++) acc[i][j] = 0.f;
  #pragma unroll 4
  for (int k = 0; k < 64; k++) {
    float4 w = *(const float4*)&Ws[k*64 + c0];
    #pragma unroll
    for (int i = 0; i < 4; i++) {
      float x = Xs[(n0+i)*65 + k];
      acc[i][0] = fmaf(x, w.x, acc[i][0]);
      acc[i][1] = fmaf(x, w.y, acc[i][1]);
      acc[i][2] = fmaf(x, w.z, acc[i][2]);
      acc[i][3] = fmaf(x, w.w, acc[i][3]);
    }
  }
  float l0=al[c0], l1=al[c0+1], l2=al[c0+2], l3=al[c0+3];
  float r0=ar[c0], r1=ar[c0+1], r2=ar[c0+2], r3=ar[c0+3];
  #pragma unroll
  for (int i = 0; i < 4; i++) {
    int g = nbase + n0 + i;
    if (g < n) *(ushort4*)&feat[(size_t)g*64 + c0] =
        ushort4{bf16bits(acc[i][0]),bf16bits(acc[i][1]),bf16bits(acc[i][2]),bf16bits(acc[i][3])};
    float e = acc[i][0]*l0 + acc[i][1]*l1 + acc[i][2]*l2 + acc[i][3]*l3;
    float q = acc[i][0]*r0 + acc[i][1]*r1 + acc[i][2]*r2 + acc[i][3]*r3;
    e += __shfl_xor(e,1); e += __shfl_xor(e,2);
    q += __shfl_xor(q,1); q += __shfl_xor(q,2);
    if ((tid & 3) == 0 && g < n) {
      int h = (tid & 15) >> 2;
      el[g*4+h] = e; er[g*4+h] = q;
    }
  }
}

// ------- fused score-staging + softmax + aggregation, 8B/lane gather -------
// Block = 4 nodes (1/wave). Stage alpha in LDS (one exp per edge-head), then
// gather loop: lane = eg*16+q -> each lane loads dwordx2 (4 bf16 cols) of edge
// i+eg / i+4+eg; per 8 edges only 2 load instrs + 2 LDS reads per lane.
// Epilogue: eg-reduction via shfl_xor(16/32); lanes<16 hold 4 cols each.

template<int LAYER>
__global__ __launch_bounds__(256) void aggregate_fused(const int* __restrict__ off,
    const int* __restrict__ csr_src, const float* __restrict__ el, const float* __restrict__ er,
    const unsigned short* __restrict__ feat, const float* __restrict__ res,
    const float* __restrict__ bias, float* __restrict__ out, int n)
{
  __shared__ float sp[SCAP*4];     // 8KB staged alpha
  __shared__ float er_s[4][4];
  __shared__ int   so[5];
  const int tid = threadIdx.x, wave = tid >> 6, lane = tid & 63;
  const int nb = blockIdx.x*4;
  if (tid < 5) so[tid] = off[min(nb + tid, n)];
  if (tid >= 5 && tid < 21) {
    int t = tid - 5;                   // t = node*4+h over 16
    int g = nb + (t >> 2);
    er_s[t >> 2][t & 3] = (g < n) ? er[g*4 + (t & 3)] : 0.f;
  }
  __syncthreads();
  const int b0 = so[0], b4 = so[4];
  const bool staged = (b4 - b0) <= SCAP;
  if (staged) {
    const int o1 = so[1], o2 = so[2], o3 = so[3];
    for (int j = b0 + tid; j < b4; j += 256) {
      int s = csr_src[j];
      int t = (j >= o1) + (j >= o2) + (j >= o3);
      float4 l = *(const float4*)&el[s*4];
      int li = j - b0;
      sp[li*4+0] = __expf(LEAKY(l.x + er_s[t][0]));
      sp[li*4+1] = __expf(LEAKY(l.y + er_s[t][1]));
      sp[li*4+2] = __expf(LEAKY(l.z + er_s[t][2]));
      sp[li*4+3] = __expf(LEAKY(l.w + er_s[t][3]));
    }
  }
  __syncthreads();
  const int node = nb + wave;
  if (node >= n) return;
  const int q = lane & 15, eg = lane >> 4;
  const int hq = q >> 2;
  const unsigned qoff = (unsigned)q * 8u;     // byte offset of this lane's col-quad
  const char* fbase = (const char*)feat;
  const int beg = so[wave], end = so[wave+1];
  float ac0=0.f, ac1=0.f, ac2=0.f, ac3=0.f, dn0=0.f, dn1=0.f;
  int i = beg;
  if (staged) {
    for (; i + 8 <= end; i += 8) {
      int e0 = i + eg, e1 = i + 4 + eg;
      int s0 = csr_src[e0], s1 = csr_src[e1];
      float p0 = sp[(e0 - b0)*4 + hq];
      float p1 = sp[(e1 - b0)*4 + hq];
      uint2 w0 = *(const uint2*)(fbase + (((unsigned)s0 << 7) + qoff));
      uint2 w1 = *(const uint2*)(fbase + (((unsigned)s1 << 7) + qoff));
      dn0 += p0; dn1 += p1;
      ac0 = fmaf(p0, bf16lo(w0.x), ac0); ac1 = fmaf(p0, bf16hi(w0.x), ac1);
      ac2 = fmaf(p0, bf16lo(w0.y), ac2); ac3 = fmaf(p0, bf16hi(w0.y), ac3);
      ac0 = fmaf(p1, bf16lo(w1.x), ac0); ac1 = fmaf(p1, bf16hi(w1.x), ac1);
      ac2 = fmaf(p1, bf16lo(w1.y), ac2); ac3 = fmaf(p1, bf16hi(w1.y), ac3);
    }
    for (; i < end; i += 4) {
      int e = i + eg;
      bool act = e < end;
      int s = csr_src[act ? e : (end-1)];
      float p = act ? sp[(e - b0)*4 + hq] : 0.f;
      uint2 w = *(const uint2*)(fbase + (((unsigned)s << 7) + qoff));
      dn0 += p;
      ac0 = fmaf(p, bf16lo(w.x), ac0); ac1 = fmaf(p, bf16hi(w.x), ac1);
      ac2 = fmaf(p, bf16lo(w.y), ac2); ac3 = fmaf(p, bf16hi(w.y), ac3);
    }
  } else {                                   // fallback (never for this graph)
    const float erh = er_s[wave][hq];
    for (; i < end; i += 4) {
      int e = i + eg;
      bool act = e < end;
      int s = csr_src[act ? e : (end-1)];
      float p = act ? __expf(LEAKY(el[s*4 + hq] + erh)) : 0.f;
      uint2 w = *(const uint2*)(fbase + (((unsigned)s << 7) + qoff));
      dn0 += p;
      ac0 = fmaf(p, bf16lo(w.x), ac0); ac1 = fmaf(p, bf16hi(w.x), ac1);
      ac2 = fmaf(p, bf16lo(w.y), ac2); ac3 = fmaf(p, bf16hi(w.y), ac3);
    }
  }
  float den = dn0 + dn1;
  ac0 += __shfl_xor(ac0,16); ac0 += __shfl_xor(ac0,32);
  ac1 += __shfl_xor(ac1,16); ac1 += __shfl_xor(ac1,32);
  ac2 += __shfl_xor(ac2,16); ac2 += __shfl_xor(ac2,32);
  ac3 += __shfl_xor(ac3,16); ac3 += __shfl_xor(ac3,32);
  den += __shfl_xor(den,16); den += __shfl_xor(den,32);
  if (lane < 16) {
    float inv = (den > 0.f) ? (1.0f/den) : 0.f;      // empty segment -> 0
    const float4 rq = *(const float4*)&res[(size_t)node*64 + q*4];
    const float4 bq = *(const float4*)&bias[q*4];
    float v0 = ac0*inv + rq.x + bq.x;
    float v1 = ac1*inv + rq.y + bq.y;
    float v2 = ac2*inv + rq.z + bq.z;
    float v3 = ac3*inv + rq.w + bq.w;
    if (LAYER == 1) {
      v0 = (v0 > 0.f) ? v0 : expm1f(v0);
      v1 = (v1 > 0.f) ? v1 : expm1f(v1);
      v2 = (v2 > 0.f) ? v2 : expm1f(v2);
      v3 = (v3 > 0.f) ? v3 : expm1f(v3);
      *(float4*)&out[(size_t)node*64 + q*4] = float4{v0,v1,v2,v3};
    } else {
      // mean over heads: lanes q, q^4, q^8, q^12 hold same within-head col-quad
      v0 += __shfl_xor(v0,4); v0 += __shfl_xor(v0,8);
      v1 += __shfl_xor(v1,4); v1 += __shfl_xor(v1,8);
      v2 += __shfl_xor(v2,4); v2 += __shfl_xor(v2,8);
      v3 += __shfl_xor(v3,4); v3 += __shfl_xor(v3,8);
      if (q < 4)
        *(float4*)&out[(size_t)node*16 + q*4] = float4{0.25f*v0,0.25f*v1,0.25f*v2,0.25f*v3};
    }
  }
}

// ---------------- launch ----------------

extern "C" void kernel_launch(void* const* d_in, const int* in_sizes, int n_in,
                              void* d_out, int out_size, void* d_ws, size_t ws_size,
                              hipStream_t stream)
{
  (void)n_in; (void)out_size; (void)ws_size;
  const float* x   = (const float*)d_in[0];
  const int*   src = (const int*)  d_in[1];
  const int*   dst = (const int*)  d_in[2];
  const float* W1  = (const float*)d_in[3];
  const float* al1 = (const float*)d_in[4];
  const float* ar1 = (const float*)d_in[5];
  const float* rW1 = (const float*)d_in[6];
  const float* b1  = (const float*)d_in[7];
  const float* W2  = (const float*)d_in[8];
  const float* al2 = (const float*)d_in[9];
  const float* ar2 = (const float*)d_in[10];
  const float* b2  = (const float*)d_in[11];
  float* out = (float*)d_out;

  const int N_ = in_sizes[0] / 128;   // 100000
  const int E_ = in_sizes[1];         // 1600000
  const int B_ = cdiv(N_, NBK);       // 391 buckets

  char* ws = (char*)d_ws;
  size_t o = 0;
  auto alloc = [&](size_t bytes)->char* {
    char* p = ws + o; o += (bytes + 255) & ~(size_t)255; return p;
  };
  int*   acur    = (int*)  alloc((size_t)B_*4);
  int*   bbase   = (int*)  alloc(((size_t)B_+1)*4);
  int*   off     = (int*)  alloc(((size_t)N_+1)*4);
  unsigned int* tmp = (unsigned int*)alloc((size_t)B_*CAP*4);
  int*   csr_src = (int*)  alloc((size_t)E_*4);
  unsigned short* featb = (unsigned short*)alloc((size_t)N_*64*2);  // bf16
  float* el      = (float*)alloc((size_t)N_*4*4);
  float* er      = (float*)alloc((size_t)N_*4*4);
  float* hbuf    = (float*)alloc((size_t)N_*64*4);   // res1 -> layer-1 out -> layer-2 res

  // CSR build (rebuilt every call — no static state)
  hipMemsetAsync(acur, 0, (size_t)B_*4, stream);
  binA<<<256, 256, 0, stream>>>(src, dst, acur, tmp, E_, B_, cdiv(E_,256));
  bucket_scan<<<1, 512, 0, stream>>>(acur, bbase, off, B_, N_, E_);
  binC<<<B_, 256, 0, stream>>>(tmp, acur, bbase, off, csr_src, N_);

  // ---- layer 1 ----
  lin128_once<<<cdiv(N_,32), 256, 0, stream>>>(x, W1, rW1, al1, ar1, featb, el, er, hbuf, N_);
  aggregate_fused<1><<<cdiv(N_,4), 256, 0, stream>>>(off, csr_src, el, er,
      featb, hbuf, b1, hbuf, N_);

  // ---- layer 2 ----
  lin64<<<cdiv(N_,64), 256, 0, stream>>>(hbuf, W2, al2, ar2, featb, el, er, N_);
  aggregate_fused<2><<<cdiv(N_,4), 256, 0, stream>>>(off, csr_src, el, er,
      featb, hbuf, b2, out, N_);
}